// Round 15
// baseline (1109.320 us; speedup 1.0000x reference)
//
#include <hip/hip_runtime.h>
#include <hip/hip_bf16.h>

typedef unsigned short u16;
typedef __attribute__((ext_vector_type(8))) __bf16 bf16x8;
typedef __attribute__((ext_vector_type(8))) short short8;
typedef __attribute__((ext_vector_type(4))) float f32x4;

#define BB 4096
#define TT 19
#define INP 17
#define HH 1024
#define NE 4128          // 4096 permuted gate entries + 32 proj rows
#define NT_PROJ 15       // proj rows are staged/used by nt==15 blocks
#define NKTOT 33         // K-tiles: 1 x-tile + 32 h-tiles (BK=32)

// LDS map (u16 units):
//   A bufs  3 x 8192  (tile 256x32)   [0      .. 24575]
//   B bufs  2 x 8192                  [24576  .. 40959]
//   P bufs  3 x 1024  (32x32)         [40960  .. 44031]
//   c tile  256x64 f32 (linear)       [44032  .. 76799]
// Epilogue h tile [256][68] u16 reuses the A region (dead after last MFMA).
#define ABASE(b) ((b) * 8192)
#define BBASE(b) (24576 + (b) * 8192)
#define PBASE(b) (40960 + (b) * 1024)
#define CBASE 44032
#define HTS 68
#define LDS_BYTES 153600

#define FENCE asm volatile("" ::: "memory")

__device__ __forceinline__ u16 f2bfu(float f) {
    __hip_bfloat16 b = __float2bfloat16(f);
    return __builtin_bit_cast(unsigned short, b);
}
__device__ __forceinline__ float fast_sigmoid(float x) {
    return 1.f / (1.f + __expf(-x));
}
__device__ __forceinline__ float fast_tanh(float x) {
    float e = __expf(2.f * x);
    return (e - 1.f) / (e + 1.f);
}
__device__ __forceinline__ bf16x8 ldfrag(const u16* p) {
    return __builtin_bit_cast(bf16x8, *(const short8*)p);
}
// 16B-slot swizzle within a 32-elem row (involution), r10-verified
__device__ __forceinline__ int fsw(int r) { return (r ^ (r >> 2)) & 3; }

// async 16B global -> LDS (linear dest = wave base + lane*16)
__device__ __forceinline__ void cp16(const u16* l, const void* g) {
    __builtin_amdgcn_global_load_lds(
        (const __attribute__((address_space(1))) unsigned int*)g,
        (__attribute__((address_space(3))) unsigned int*)l, 16, 0, 0);
}

// ---------------- prep kernels ----------------
// wperm[NE][HH]: entry r of tile nt -> gate (r>>4)&3, hcol nt*64+(r>>6)*16+(r&15);
// rows 4096..4127 = W_lin rows (17 real + zero pad). grid MUST be 2064.
__global__ void prep_wperm(const float* __restrict__ Whh, const float* __restrict__ Wlin,
                           u16* __restrict__ wperm) {
    size_t idx = ((size_t)blockIdx.x * 256 + threadIdx.x) * 8;
    int R = (int)(idx >> 10);
    int k = (int)(idx & 1023);
    const float* src = nullptr;
    if (R < 4096) {
        int nt = R >> 8, r = R & 255;
        int qn = r >> 6, nf = (r >> 4) & 3, cj = r & 15;
        int hcol = nt * 64 + qn * 16 + cj;
        src = Whh + ((size_t)(nf * HH + hcol)) * HH + k;
    } else if (R - 4096 < INP) {
        src = Wlin + (size_t)(R - 4096) * HH + k;
    }
#pragma unroll
    for (int e = 0; e < 8; ++e) wperm[idx + e] = src ? f2bfu(src[e]) : (u16)0;
}

// wx32[NE][32]: same row permutation of W_ih, K padded 17->32. grid 516.
__global__ void prep_wx(const float* __restrict__ Wih, u16* __restrict__ wx32) {
    int idx = blockIdx.x * 256 + threadIdx.x;
    int R = idx >> 5, k = idx & 31;
    u16 v = 0;
    if (R < 4096 && k < INP) {
        int nt = R >> 8, r = R & 255;
        int qn = r >> 6, nf = (r >> 4) & 3, cj = r & 15;
        int hcol = nt * 64 + qn * 16 + cj;
        v = f2bfu(Wih[(size_t)(nf * HH + hcol) * INP + k]);
    }
    wx32[idx] = v;
}

// bias[4096] = b_ih + b_hh. grid 16.
__global__ void prep_bias(const float* __restrict__ bih, const float* __restrict__ bhh,
                          float* __restrict__ bias) {
    int idx = blockIdx.x * 256 + threadIdx.x;
    bias[idx] = bih[idx] + bhh[idx];
}

// xpad[t][b][32]. grid 9728 (t slots 0..18; slot 19 memset to 0).
__global__ void prep_x(const float* __restrict__ x, u16* __restrict__ xpad) {
    int idx = blockIdx.x * 256 + threadIdx.x;
    int c = idx & 31;
    int rb = idx >> 5;
    int t = rb >> 12;
    int b = rb & 4095;
    xpad[idx] = (c < INP) ? f2bfu(x[((size_t)b * TT + t) * INP + c]) : (u16)0;
}

// ------- fused step kernel: 256x256, BK=32, 2-ahead counted pipeline -------
// grid 256 = 16 mt x 16 nt (XCD 2D-chunked), 512 threads = 8 waves (2qr x 4qn).
// A (h) 3-buf staged 2 tiles ahead; B (W) 2-buf 1 ahead; P with A; c staged
// once at prologue into dedicated LDS. Per iter: stage B(j+1), A(j+2), P(j+2);
// s_waitcnt vmcnt(6|8) (B(j) forced complete, deeper loads in flight);
// barrier; MFMA; barrier. Epilogue: cell vs LDS c; coalesced h/c stores.
__global__ __launch_bounds__(512, 2) void lstm_step(
    const u16* __restrict__ h_in, u16* __restrict__ h_out,
    float* __restrict__ c_buf, const u16* __restrict__ wperm,
    const u16* __restrict__ wx32, const float* __restrict__ bias,
    const u16* __restrict__ xpad, const float* __restrict__ blin,
    float* __restrict__ outp, float* __restrict__ h_fin,
    int t, int is_last, int tail)
{
    extern __shared__ u16 lds[];

    const int tid = threadIdx.x;
    const int lane = tid & 63;
    const int wv = tid >> 6;
    const int qr = wv >> 2, qn = wv & 3;
    const int r16 = lane & 15, s4 = lane >> 4;

    int mt, nt;
    if (tail) { mt = blockIdx.x; nt = NT_PROJ; }
    else {
        const int xcd = blockIdx.x & 7, local = blockIdx.x >> 3;
        mt = (xcd >> 2) * 8 + (local & 7);
        nt = (xcd & 3) * 4 + (local >> 3);
    }
    const int m0 = mt * 256;
    const size_t R0 = (size_t)nt * 256;
    const bool my_proj = (nt == NT_PROJ) && (qn < 2);
    const bool pwave = (nt == NT_PROJ) && (wv < 2);   // waves staging P
    const int NK = (tail || t > 0) ? NKTOT : 1;       // t==0: x-tile only

    // staging coords: A/B slots tid and tid+512; slot d -> row d>>2, chunk d&3.
    const int sr0 = tid >> 2, sr1 = sr0 + 128;
    const int xo0 = ((tid & 3) ^ fsw(sr0)) * 8;
    const int xo1 = ((tid & 3) ^ fsw(sr1)) * 8;
    const u16* hA0 = h_in + (size_t)(m0 + sr0) * HH + xo0;
    const u16* hA1 = h_in + (size_t)(m0 + sr1) * HH + xo1;
    const u16* wB0 = wperm + (R0 + sr0) * HH + xo0;
    const u16* wB1 = wperm + (R0 + sr1) * HH + xo1;
    const int prow = (tid >> 2) & 31;
    const int pxo = ((tid & 3) ^ fsw(prow)) * 8;
    const u16* wP = wperm + (size_t)(4096 + prow) * HH + pxo;

    // fragment read offsets (swizzled)
    int aoff[8], boff[4], poff;
#pragma unroll
    for (int mf = 0; mf < 8; ++mf) {
        int r = qr * 128 + mf * 16 + r16;
        aoff[mf] = r * 32 + (s4 ^ fsw(r)) * 8;
    }
#pragma unroll
    for (int nf = 0; nf < 4; ++nf) {
        int r = qn * 64 + nf * 16 + r16;
        boff[nf] = r * 32 + (s4 ^ fsw(r)) * 8;
    }
    {
        int r = qn * 16 + r16;
        poff = r * 32 + (s4 ^ fsw(r)) * 8;
    }

    // acc init with bias
    f32x4 acc[8][4];
    const int n = nt * 64 + qn * 16 + r16;
    if (!tail) {
#pragma unroll
        for (int nf = 0; nf < 4; ++nf) {
            float bv = bias[nf * HH + n];
#pragma unroll
            for (int mf = 0; mf < 8; ++mf) acc[mf][nf] = (f32x4){bv, bv, bv, bv};
        }
    }
    f32x4 pacc[8];
    const int p = qn * 16 + r16;
    if (my_proj) {
        float pv = (p < INP) ? blin[p] : 0.f;
#pragma unroll
        for (int mf = 0; mf < 8; ++mf) pacc[mf] = (f32x4){pv, pv, pv, pv};
    }

    // ---- prologue: c (once), tile0 (x | wx32), tile1 A/P ----
    if (!tail) {
#pragma unroll
        for (int i = 0; i < 8; ++i) {
            const int s = tid + i * 512;
            cp16(&lds[CBASE + s * 8],
                 c_buf + (size_t)(m0 + (s >> 4)) * HH + nt * 64 + (s & 15) * 4);
        }
    }
    const u16* xA = xpad + ((size_t)t * BB + m0) * 32;
    cp16(&lds[ABASE(0) + tid * 8],         xA + (size_t)sr0 * 32 + xo0);
    cp16(&lds[ABASE(0) + (tid + 512) * 8], xA + (size_t)sr1 * 32 + xo1);
    cp16(&lds[BBASE(0) + tid * 8],         wx32 + (R0 + sr0) * 32 + xo0);
    cp16(&lds[BBASE(0) + (tid + 512) * 8], wx32 + (R0 + sr1) * 32 + xo1);
    if (NK > 1) {
        cp16(&lds[ABASE(1) + tid * 8],         hA0);      // tile 1, K 0..31
        cp16(&lds[ABASE(1) + (tid + 512) * 8], hA1);
        if (pwave) cp16(&lds[PBASE(1) + tid * 8], wP);
    }

    // ---- pipeline over NK K-tiles ----
    for (int j = 0; j < NK; ++j) {
        if (j <= NK - 3) {
            // B first (1-ahead) so vmcnt(6/8) forces B(j) complete
            cp16(&lds[BBASE((j + 1) & 1) + tid * 8],         wB0 + j * 32);
            cp16(&lds[BBASE((j + 1) & 1) + (tid + 512) * 8], wB1 + j * 32);
            const int ko = (j + 1) * 32;                  // A tile j+2 source
            const int a2 = (j + 2) % 3;
            cp16(&lds[ABASE(a2) + tid * 8],         hA0 + ko);
            cp16(&lds[ABASE(a2) + (tid + 512) * 8], hA1 + ko);
            if (pwave) {
                cp16(&lds[PBASE(a2) + tid * 8], wP + ko);
                asm volatile("s_waitcnt vmcnt(8)" ::: "memory");
            } else {
                asm volatile("s_waitcnt vmcnt(6)" ::: "memory");
            }
        } else if (j == NK - 2) {
            cp16(&lds[BBASE((j + 1) & 1) + tid * 8],         wB0 + j * 32);
            cp16(&lds[BBASE((j + 1) & 1) + (tid + 512) * 8], wB1 + j * 32);
            if (pwave) asm volatile("s_waitcnt vmcnt(5)" ::: "memory");
            else       asm volatile("s_waitcnt vmcnt(4)" ::: "memory");
        } else {
            asm volatile("s_waitcnt vmcnt(0)" ::: "memory");
        }
        __builtin_amdgcn_s_barrier();
        FENCE;

        const int cbA = ABASE(j % 3), cbB = BBASE(j & 1), cbP = PBASE(j % 3);
        const bool do_p = my_proj && (j > 0);
        __builtin_amdgcn_s_setprio(1);
        bf16x8 b[4];
        if (!tail) {
#pragma unroll
            for (int nf = 0; nf < 4; ++nf) b[nf] = ldfrag(&lds[cbB + boff[nf]]);
        }
        bf16x8 pb;
        if (do_p) pb = ldfrag(&lds[cbP + poff]);
#pragma unroll
        for (int mf = 0; mf < 8; ++mf) {
            bf16x8 a = ldfrag(&lds[cbA + aoff[mf]]);
            if (!tail) {
#pragma unroll
                for (int nf = 0; nf < 4; ++nf)
                    acc[mf][nf] = __builtin_amdgcn_mfma_f32_16x16x32_bf16(
                        a, b[nf], acc[mf][nf], 0, 0, 0);
            }
            if (do_p)
                pacc[mf] = __builtin_amdgcn_mfma_f32_16x16x32_bf16(
                    a, pb, pacc[mf], 0, 0, 0);
        }
        __builtin_amdgcn_s_setprio(0);
        FENCE;
        __builtin_amdgcn_s_barrier();
        FENCE;
    }

    // ---- epilogue: cell vs LDS c; h tile (stride 68) in dead A region ----
    if (!tail) {
        float* cf = (float*)&lds[CBASE];
        const int cl = qn * 16 + r16;
#pragma unroll
        for (int mf = 0; mf < 8; ++mf)
#pragma unroll
            for (int j4 = 0; j4 < 4; ++j4) {
                int rl = qr * 128 + mf * 16 + s4 * 4 + j4;
                float iv = fast_sigmoid(acc[mf][0][j4]);
                float fv = fast_sigmoid(acc[mf][1][j4]);
                float gv = fast_tanh(acc[mf][2][j4]);
                float ov = fast_sigmoid(acc[mf][3][j4]);
                float cold = cf[rl * 64 + cl];
                float cnew = fv * cold + iv * gv;
                float hnew = ov * fast_tanh(cnew);
                cf[rl * 64 + cl] = cnew;
                lds[rl * HTS + cl] = f2bfu(hnew);
                if (is_last)
                    __builtin_nontemporal_store(
                        hnew, &h_fin[(size_t)(m0 + rl) * HH + n]);
            }
        __syncthreads();
        // coalesced stores: wave wv owns rows wv*32..+31; lane = col.
#pragma unroll 4
        for (int r = 0; r < 32; ++r) {
            const int rl = wv * 32 + r;
            const size_t gi = (size_t)(m0 + rl) * HH + nt * 64 + lane;
            c_buf[gi] = cf[rl * 64 + lane];
            h_out[gi] = lds[rl * HTS + lane];
        }
    }
    // ---- proj store: out_{t-1} ----
    if (my_proj && t > 0 && p < INP) {
#pragma unroll
        for (int mf = 0; mf < 8; ++mf)
#pragma unroll
            for (int j4 = 0; j4 < 4; ++j4) {
                int row = m0 + qr * 128 + mf * 16 + s4 * 4 + j4;
                __builtin_nontemporal_store(
                    pacc[mf][j4], &outp[((size_t)row * TT + (t - 1)) * INP + p]);
            }
    }
}

// ---------------- launch ----------------
extern "C" void kernel_launch(void* const* d_in, const int* in_sizes, int n_in,
                              void* d_out, int out_size, void* d_ws, size_t ws_size,
                              hipStream_t stream)
{
    const float* x    = (const float*)d_in[0];
    const float* Wih  = (const float*)d_in[1];
    const float* Whh  = (const float*)d_in[2];
    const float* bih  = (const float*)d_in[3];
    const float* bhh  = (const float*)d_in[4];
    const float* Wlin = (const float*)d_in[5];
    const float* blin = (const float*)d_in[6];
    float* out = (float*)d_out;

    char* ws = (char*)d_ws;
    u16* hb0     = (u16*)(ws);                     //  8,388,608 B
    u16* hb1     = (u16*)(ws +  8388608);          //  8,388,608 B
    u16* xpad    = (u16*)(ws + 16777216);          //  5,242,880 B (20 t-slots)
    u16* wperm   = (u16*)(ws + 22020096);          //  8,454,144 B (4128 x 1024)
    u16* wx32    = (u16*)(ws + 30474240);          //    264,192 B (4128 x 32)
    float* bias  = (float*)(ws + 30738432);        //     16,384 B

    float* h_fin = out + (size_t)BB * TT * INP;    // h_fin region
    float* c_buf = h_fin + (size_t)BB * HH;        // c_fin region = c state

    hipFuncSetAttribute((const void*)lstm_step,
                        hipFuncAttributeMaxDynamicSharedMemorySize, LDS_BYTES);

    hipMemsetAsync(c_buf, 0, (size_t)BB * HH * sizeof(float), stream);
    hipMemsetAsync((char*)xpad + (size_t)19 * BB * 32 * 2, 0, BB * 32 * 2, stream);

    prep_wperm<<<2064, 256, 0, stream>>>(Whh, Wlin, wperm);
    prep_wx<<<516, 256, 0, stream>>>(Wih, wx32);
    prep_bias<<<16, 256, 0, stream>>>(bih, bhh, bias);
    prep_x<<<9728, 256, 0, stream>>>(x, xpad);

    for (int t = 0; t < TT; ++t) {
        const u16* hin = (t & 1) ? hb1 : hb0;
        u16* hout = (t & 1) ? hb0 : hb1;
        lstm_step<<<256, 512, LDS_BYTES, stream>>>(
            hin, hout, c_buf, wperm, wx32, bias, xpad, blin, out,
            h_fin, t, (t == TT - 1) ? 1 : 0, 0);
    }
    // tail: out_18 = h_19 @ W_lin^T + b_lin  (h_19 is in hb1 after t=18)
    lstm_step<<<16, 512, LDS_BYTES, stream>>>(
        hb1, hb0, c_buf, wperm, wx32, bias, xpad, blin, out,
        h_fin, TT, 0, 1);
}